// Round 1
// 383.926 us; speedup vs baseline: 1.0903x; 1.0903x over previous
//
#include <hip/hip_runtime.h>
#include <hip/hip_bf16.h>
#include <math.h>

namespace {
constexpr int kDModel = 2048;
constexpr int kHeads  = 32;
constexpr int kState  = 64;
constexpr int kP      = 64;    // head dim = D_MODEL / N_HEADS
constexpr int kChunk  = 256;
constexpr int kNChunk = 16;    // SEQLEN / CHUNK
constexpr int kBatch  = 2;
constexpr int kSeq    = 4096;
constexpr int kM      = kBatch * kSeq;  // 8192 rows
}

typedef __bf16 bf16_t;
typedef __attribute__((ext_vector_type(8))) __bf16 bf16x8;
typedef __attribute__((ext_vector_type(4))) __bf16 bf16x4;
typedef __attribute__((ext_vector_type(4))) float f32x4;

__device__ __forceinline__ void gload_lds16(const void* g, void* l) {
    __builtin_amdgcn_global_load_lds(
        (const __attribute__((address_space(1))) void*)g,
        (__attribute__((address_space(3))) void*)l,
        16, 0, 0);
}

// ---------------------------------------------------------------------------
// MFMA bf16 GEMM (m97-structure, kept for the B/C/dt projection only).
// MODE 1: BCdt split epilogue -> bf16 B (o0h), bf16 C (o1h), fp32 softplus dt.
// ---------------------------------------------------------------------------
template <int MODE>
__global__ __launch_bounds__(256)
void gemm_mfma(const bf16_t* __restrict__ A, const bf16_t* __restrict__ W,
               int K, int N,
               const float* __restrict__ b0, const float* __restrict__ b1,
               const float* __restrict__ b2,
               float* __restrict__ o0f, bf16_t* __restrict__ o0h,
               bf16_t* __restrict__ o1h, float* __restrict__ o2f)
{
    __shared__ __bf16 AstS[128 * 32];
    __shared__ __bf16 WstS[128 * 32];
    const int tid  = threadIdx.x;
    const int lane = tid & 63;
    const int wave = tid >> 6;
    const int wm = (wave >> 1) * 64;
    const int wn = (wave & 1) * 64;
    const int l15 = lane & 15, quad = lane >> 4;
    const int m0 = blockIdx.y * 128;
    const int n0 = blockIdx.x * 128;
    const int u0 = tid, u1 = tid + 256;   // 16B staging units

    f32x4 acc[4][4];
    #pragma unroll
    for (int i = 0; i < 4; ++i)
        #pragma unroll
        for (int j = 0; j < 4; ++j)
            acc[i][j] = (f32x4){0.f, 0.f, 0.f, 0.f};

    for (int k0 = 0; k0 < K; k0 += 32) {
        gload_lds16(A + (size_t)(m0 + (u0 >> 2)) * K + k0 + (u0 & 3) * 8, AstS + u0 * 8);
        gload_lds16(A + (size_t)(m0 + (u1 >> 2)) * K + k0 + (u1 & 3) * 8, AstS + u1 * 8);
        gload_lds16(W + (size_t)(n0 + (u0 >> 2)) * K + k0 + (u0 & 3) * 8, WstS + u0 * 8);
        gload_lds16(W + (size_t)(n0 + (u1 >> 2)) * K + k0 + (u1 & 3) * 8, WstS + u1 * 8);
        __syncthreads();
        bf16x8 af[4], bfr[4];
        #pragma unroll
        for (int mi = 0; mi < 4; ++mi)
            af[mi] = *reinterpret_cast<const bf16x8*>(&AstS[(wm + mi * 16 + l15) * 32 + quad * 8]);
        #pragma unroll
        for (int ni = 0; ni < 4; ++ni)
            bfr[ni] = *reinterpret_cast<const bf16x8*>(&WstS[(wn + ni * 16 + l15) * 32 + quad * 8]);
        #pragma unroll
        for (int mi = 0; mi < 4; ++mi)
            #pragma unroll
            for (int ni = 0; ni < 4; ++ni)
                acc[mi][ni] = __builtin_amdgcn_mfma_f32_16x16x32_bf16(
                    af[mi], bfr[ni], acc[mi][ni], 0, 0, 0);
        __syncthreads();
    }

    // C/D layout: col = lane&15, row = quad*4 + reg  [m89-verified]
    #pragma unroll
    for (int mi = 0; mi < 4; ++mi) {
        #pragma unroll
        for (int reg = 0; reg < 4; ++reg) {
            const int r = m0 + wm + mi * 16 + quad * 4 + reg;
            #pragma unroll
            for (int ni = 0; ni < 4; ++ni) {
                const float v = acc[mi][ni][reg];
                if (MODE == 0) {
                    const int c = n0 + wn + ni * 16 + l15;
                    o0f[(size_t)r * N + c] = v + b0[c];
                } else {
                    const int n = n0 + wn + ni * 16 + l15;
                    if (n < 64) {
                        o0h[(size_t)r * 64 + n] = (bf16_t)(v + b0[n]);
                    } else if (n < 128) {
                        o1h[(size_t)r * 64 + (n - 64)] = (bf16_t)(v + b1[n - 64]);
                    } else if (n < 160) {
                        float z = v + b2[n - 128];
                        o2f[(size_t)r * 32 + (n - 128)] = (z > 20.f) ? z : log1pf(expf(z));
                    }
                }
            }
        }
    }
}

// ---------------------------------------------------------------------------
// NEW out-projection GEMM: 256x256 tile, BK=32, 8 waves (2Mx4N), triple-
// buffered LDS (96KB), raw s_barrier + counted vmcnt(4) (never drain-0 in
// steady state), slot-major ("k8-major") LDS layout -> conflict-free
// ds_read_b128, coalesced global_load_lds from slot-major-packed operands.
//   Ap[ks][m][8] : Ap[((ks)*M + m)*8 + j] = A[m][ks*8+j]   (ks = k/8)
//   Bp[ks][n][8] : Bp[((ks)*N + n)*8 + j] = W[n][ks*8+j]
// C[M,N] fp32 = A @ W^T + bias.
// Grid = 256 blocks (32 m-tiles x 8 n-tiles), XCD-swizzled so each XCD owns
// one n-panel (1MB of W, L2-resident).
// ---------------------------------------------------------------------------
__global__ __launch_bounds__(512, 2)
void gemm256_out(const bf16_t* __restrict__ Ap, const bf16_t* __restrict__ Bp,
                 const float* __restrict__ bias, float* __restrict__ C)
{
    constexpr int M = 8192, N = 2048, NT = 2048 / 32;  // 64 K-tiles
    __shared__ __bf16 Ab[3][4 * 256 * 8];   // [buf][q*256 + row][8]
    __shared__ __bf16 Bb[3][4 * 256 * 8];
    const int tid  = threadIdx.x;
    const int lane = tid & 63;
    const int wave = tid >> 6;
    const int l15 = lane & 15, quad = lane >> 4;
    // bijective XCD swizzle (256 % 8 == 0): XCD x gets n-tile x, all m-tiles
    const int swz = ((blockIdx.x & 7) << 5) | (blockIdx.x >> 3);
    const int m0 = (swz & 31) * 256;
    const int n0 = (swz >> 5) * 256;
    const int wm = (wave >> 2) * 128;   // 0 or 128
    const int wn = (wave & 3) * 64;     // 0,64,128,192

    const int u0 = tid, u1 = tid + 512;   // staging 16B units, q = u>>8, r = u&255
    auto stage = [&](int t2, int stb) {
        const int ks0 = t2 * 4;
        const bf16_t* As = Ap + ((size_t)ks0 * M + m0) * 8;
        const bf16_t* Bs = Bp + ((size_t)ks0 * N + n0) * 8;
        __bf16* Al = &Ab[stb][0];
        __bf16* Bl = &Bb[stb][0];
        gload_lds16(As + ((size_t)(u0 >> 8) * M + (u0 & 255)) * 8, Al + u0 * 8);
        gload_lds16(As + ((size_t)(u1 >> 8) * M + (u1 & 255)) * 8, Al + u1 * 8);
        gload_lds16(Bs + ((size_t)(u0 >> 8) * N + (u0 & 255)) * 8, Bl + u0 * 8);
        gload_lds16(Bs + ((size_t)(u1 >> 8) * N + (u1 & 255)) * 8, Bl + u1 * 8);
    };

    f32x4 acc[8][4];
    #pragma unroll
    for (int i = 0; i < 8; ++i)
        #pragma unroll
        for (int j = 0; j < 4; ++j)
            acc[i][j] = (f32x4){0.f, 0.f, 0.f, 0.f};

    // prologue: tiles 0 and 1 in flight; wait for tile 0 (4 newest may fly)
    stage(0, 0);
    stage(1, 1);
    asm volatile("s_waitcnt vmcnt(4)" ::: "memory");
    __builtin_amdgcn_s_barrier();

    int cur = 0;
    for (int t = 0; t < NT; ++t) {
        const __bf16* Ac = &Ab[cur][0];
        const __bf16* Bc = &Bb[cur][0];
        int stb = cur + 2; if (stb >= 3) stb -= 3;

        // ---- phase A: frags (rows wm..wm+63) + all B frags; prefetch t+2
        bf16x8 af[4], bfr[4];
        #pragma unroll
        for (int mi = 0; mi < 4; ++mi)
            af[mi] = *reinterpret_cast<const bf16x8*>(
                &Ac[(quad * 256 + wm + mi * 16 + l15) * 8]);
        #pragma unroll
        for (int nj = 0; nj < 4; ++nj)
            bfr[nj] = *reinterpret_cast<const bf16x8*>(
                &Bc[(quad * 256 + wn + nj * 16 + l15) * 8]);
        if (t < NT - 2) stage(t + 2, stb);
        __builtin_amdgcn_s_setprio(1);
        #pragma unroll
        for (int mi = 0; mi < 4; ++mi)
            #pragma unroll
            for (int nj = 0; nj < 4; ++nj)
                acc[mi][nj] = __builtin_amdgcn_mfma_f32_16x16x32_bf16(
                    af[mi], bfr[nj], acc[mi][nj], 0, 0, 0);
        __builtin_amdgcn_s_setprio(0);

        // ---- phase B: frags (rows wm+64..wm+127), reuse B frags
        #pragma unroll
        for (int mi = 0; mi < 4; ++mi)
            af[mi] = *reinterpret_cast<const bf16x8*>(
                &Ac[(quad * 256 + wm + 64 + mi * 16 + l15) * 8]);
        __builtin_amdgcn_s_setprio(1);
        #pragma unroll
        for (int mi = 0; mi < 4; ++mi)
            #pragma unroll
            for (int nj = 0; nj < 4; ++nj)
                acc[4 + mi][nj] = __builtin_amdgcn_mfma_f32_16x16x32_bf16(
                    af[mi], bfr[nj], acc[4 + mi][nj], 0, 0, 0);
        __builtin_amdgcn_s_setprio(0);

        // ---- tile boundary: tile t+1 must be landed; t+2's 4 loads may fly
        if (t < NT - 2) {
            asm volatile("s_waitcnt vmcnt(4)" ::: "memory");
        } else if (t < NT - 1) {
            asm volatile("s_waitcnt vmcnt(0)" ::: "memory");
        }
        if (t < NT - 1) __builtin_amdgcn_s_barrier();
        cur = cur + 1; if (cur == 3) cur = 0;
    }

    // epilogue: C = acc + bias
    float bia[4];
    #pragma unroll
    for (int nj = 0; nj < 4; ++nj) bia[nj] = bias[n0 + wn + nj * 16 + l15];
    #pragma unroll
    for (int mi = 0; mi < 8; ++mi) {
        #pragma unroll
        for (int reg = 0; reg < 4; ++reg) {
            const int r = m0 + wm + mi * 16 + quad * 4 + reg;
            #pragma unroll
            for (int nj = 0; nj < 4; ++nj) {
                const int c = n0 + wn + nj * 16 + l15;
                C[(size_t)r * N + c] = acc[mi][nj][reg] + bia[nj];
            }
        }
    }
}

// float -> bf16 convert, 4 elems/thread
__global__ __launch_bounds__(256)
void cvt_bf16_kernel(const float* __restrict__ src, bf16_t* __restrict__ dst, int n)
{
    const int i = (blockIdx.x * 256 + threadIdx.x) * 4;
    if (i + 3 < n) {
        const float4 v = *reinterpret_cast<const float4*>(src + i);
        dst[i + 0] = (bf16_t)v.x;
        dst[i + 1] = (bf16_t)v.y;
        dst[i + 2] = (bf16_t)v.z;
        dst[i + 3] = (bf16_t)v.w;
    }
}

// out_w fp32 [2048][2048] (row n, col k) -> slot-major bf16 Wp[ks][n][8]
__global__ __launch_bounds__(256)
void pack_wob_kernel(const float* __restrict__ W, bf16_t* __restrict__ Wp)
{
    const int idx = blockIdx.x * 256 + threadIdx.x;   // 2048*256 units of 16B
    const int n = idx >> 8, ks = idx & 255;           // coalesced reads
    const float4 v0 = *reinterpret_cast<const float4*>(W + (size_t)n * 2048 + ks * 8);
    const float4 v1 = *reinterpret_cast<const float4*>(W + (size_t)n * 2048 + ks * 8 + 4);
    bf16x8 o;
    o[0] = (__bf16)v0.x; o[1] = (__bf16)v0.y; o[2] = (__bf16)v0.z; o[3] = (__bf16)v0.w;
    o[4] = (__bf16)v1.x; o[5] = (__bf16)v1.y; o[6] = (__bf16)v1.z; o[7] = (__bf16)v1.w;
    *reinterpret_cast<bf16x8*>(Wp + ((size_t)ks * 2048 + n) * 8) = o;
}

// Concat [B_w;C_w;dt_w] into bf16 [256,2048], rows 160..255 zero
__global__ __launch_bounds__(256)
void pack_w_kernel(const float* __restrict__ B_w, const float* __restrict__ C_w,
                   const float* __restrict__ dt_w, bf16_t* __restrict__ wcat)
{
    const int idx = blockIdx.x * 256 + threadIdx.x;   // 256*2048 total
    const int r = idx >> 11, k = idx & 2047;
    float v = 0.f;
    if (r < 64)       v = B_w[r * 2048 + k];
    else if (r < 128) v = C_w[(r - 64) * 2048 + k];
    else if (r < 160) v = dt_w[(r - 128) * 2048 + k];
    wcat[idx] = (bf16_t)v;
}

// Per (b,h,chunk): Acs[l] = inclusive cumsum_l( dt[l] * A[h] ), A = -exp(A_log)
__global__ __launch_bounds__(kChunk)
void dtcumsum_kernel(const float* __restrict__ dtm, const float* __restrict__ A_log,
                     float* __restrict__ Acs)
{
    const int blk = blockIdx.x;                  // (bi*kHeads+hi)*kNChunk + ci
    const int ci = blk & (kNChunk - 1);
    const int hi = (blk >> 4) & (kHeads - 1);
    const int bi = blk >> 9;
    const int t = threadIdx.x;
    const float Ah = -expf(A_log[hi]);
    __shared__ float s[kChunk];
    s[t] = dtm[((size_t)bi * kSeq + ci * kChunk + t) * kHeads + hi] * Ah;
    __syncthreads();
    for (int off = 1; off < kChunk; off <<= 1) {
        const float add = (t >= off) ? s[t - off] : 0.f;
        __syncthreads();
        s[t] += add;
        __syncthreads();
    }
    Acs[((size_t)(bi * kHeads + hi) * kNChunk + ci) * kChunk + t] = s[t];
}

// Transpose one chunk of B: bTg[b,c][n][l] = Bb16[(b,c,l)][n]
__global__ __launch_bounds__(256)
void bT_kernel(const bf16_t* __restrict__ Bb16, bf16_t* __restrict__ bTg)
{
    const int ci = blockIdx.x & (kNChunk - 1);
    const int bi = blockIdx.x >> 4;
    const size_t rowbase = (size_t)bi * kSeq + ci * kChunk;
    __shared__ __bf16 T[64 * 264];
    const int tid = threadIdx.x;        // = row l
    bf16x8 v[8];
    #pragma unroll
    for (int e = 0; e < 8; ++e)
        v[e] = *reinterpret_cast<const bf16x8*>(Bb16 + (rowbase + tid) * 64 + e * 8);
    #pragma unroll
    for (int e = 0; e < 8; ++e)
        #pragma unroll
        for (int j = 0; j < 8; ++j)
            T[(e * 8 + j) * 264 + tid] = v[e][j];
    __syncthreads();
    const int n = tid >> 2, seg = (tid & 3) * 64;
    bf16_t* dst = bTg + ((size_t)(bi * kNChunk + ci)) * (64 * 256) + n * 256 + seg;
    #pragma unroll
    for (int j = 0; j < 8; ++j) {
        *reinterpret_cast<bf16x8*>(dst + j * 8) =
            *reinterpret_cast<const bf16x8*>(&T[n * 264 + seg + j * 8]);
    }
}

// xdtT[(b,c,h)][p][l] = bf16( xb[t, h*64+p] * dt[t,h] ),  t = rowbase+l
__global__ __launch_bounds__(256)
void xdtT_kernel(const bf16_t* __restrict__ xb, const float* __restrict__ dtm,
                 bf16_t* __restrict__ xdtT)
{
    const int blk = blockIdx.x;                  // (bi*16+ci)*32+hi
    const int hi = blk & (kHeads - 1);
    const int ci = (blk >> 5) & (kNChunk - 1);
    const int bi = blk >> 9;
    const size_t rowbase = (size_t)bi * kSeq + ci * kChunk;
    __shared__ __bf16 T[64 * 264];
    const int tid = threadIdx.x;        // = row l
    const float d = dtm[(rowbase + tid) * kHeads + hi];
    bf16x8 v[8];
    #pragma unroll
    for (int e = 0; e < 8; ++e)
        v[e] = *reinterpret_cast<const bf16x8*>(xb + (rowbase + tid) * kDModel + hi * kP + e * 8);
    #pragma unroll
    for (int e = 0; e < 8; ++e)
        #pragma unroll
        for (int j = 0; j < 8; ++j)
            T[(e * 8 + j) * 264 + tid] = (__bf16)((float)v[e][j] * d);
    __syncthreads();
    const int p = tid >> 2, seg = (tid & 3) * 64;
    bf16_t* dst = xdtT + (size_t)blk * (64 * 256) + p * 256 + seg;
    #pragma unroll
    for (int j = 0; j < 8; ++j) {
        *reinterpret_cast<bf16x8*>(dst + j * 8) =
            *reinterpret_cast<const bf16x8*>(&T[p * 264 + seg + j * 8]);
    }
}

// ---------------------------------------------------------------------------
// MFMA chunk states: states[(b,c,h)][p][n] = sum_l xdtT[p][l]*dec[l]*B[l][n]
// ---------------------------------------------------------------------------
__global__ __launch_bounds__(256)
void states_mfma(const bf16_t* __restrict__ xdtT, const bf16_t* __restrict__ bTg,
                 const float* __restrict__ Acs, float* __restrict__ states)
{
    const int blk = blockIdx.x;                  // (bi*16+ci)*32+hi
    const int hi = blk & (kHeads - 1);
    const int ci = (blk >> 5) & (kNChunk - 1);
    const int bi = blk >> 9;
    __shared__ __bf16 Xa[64 * 264];
    __shared__ __bf16 Bt[64 * 264];
    __shared__ float dec[kChunk];
    const int tid = threadIdx.x;
    const int lane = tid & 63;
    const int wave = tid >> 6;
    const int l15 = lane & 15, quad = lane >> 4;

    const float* acs = Acs + ((size_t)(bi * kHeads + hi) * kNChunk + ci) * kChunk;
    dec[tid] = expf(acs[kChunk - 1] - acs[tid]);   // <= 1
    __syncthreads();

    const bf16_t* bsrc = bTg + ((size_t)(bi * kNChunk + ci)) * (64 * 256);
    const bf16_t* xsrc = xdtT + (size_t)blk * (64 * 256);
    #pragma unroll
    for (int e = 0; e < 8; ++e) {
        const int u = e * 256 + tid;
        const int r = u >> 5, seg = (u & 31) * 8;
        *reinterpret_cast<bf16x8*>(&Bt[r * 264 + seg]) =
            *reinterpret_cast<const bf16x8*>(bsrc + r * 256 + seg);
        bf16x8 xv = *reinterpret_cast<const bf16x8*>(xsrc + r * 256 + seg);
        bf16x8 xo;
        #pragma unroll
        for (int j = 0; j < 8; ++j)
            xo[j] = (__bf16)((float)xv[j] * dec[seg + j]);
        *reinterpret_cast<bf16x8*>(&Xa[r * 264 + seg]) = xo;
    }
    __syncthreads();

    f32x4 acc[4];
    #pragma unroll
    for (int ni = 0; ni < 4; ++ni) acc[ni] = (f32x4){0.f, 0.f, 0.f, 0.f};
    #pragma unroll
    for (int kk = 0; kk < 8; ++kk) {
        const bf16x8 af = *reinterpret_cast<const bf16x8*>(
            &Xa[(wave * 16 + l15) * 264 + kk * 32 + quad * 8]);
        #pragma unroll
        for (int ni = 0; ni < 4; ++ni) {
            const bf16x8 bf = *reinterpret_cast<const bf16x8*>(
                &Bt[(ni * 16 + l15) * 264 + kk * 32 + quad * 8]);
            acc[ni] = __builtin_amdgcn_mfma_f32_16x16x32_bf16(af, bf, acc[ni], 0, 0, 0);
        }
    }
    float* sp = states + (size_t)blk * (kP * kState);
    #pragma unroll
    for (int reg = 0; reg < 4; ++reg) {
        const int p = wave * 16 + quad * 4 + reg;
        #pragma unroll
        for (int ni = 0; ni < 4; ++ni)
            sp[(size_t)p * kState + ni * 16 + l15] = acc[ni][reg];
    }
}

// prevs[b,0,h]=0 ; prevs[b,c,h] = exp(a[c-1])*prevs[b,c-1,h] + states[b,c-1,h]
__global__ __launch_bounds__(256)
void chunkscan_kernel(const float* __restrict__ states, const float* __restrict__ Acs,
                      float* __restrict__ prevs)
{
    const int hi = blockIdx.x & (kHeads - 1);
    const int bi = blockIdx.x >> 5;
    const int tid = threadIdx.x;
    __shared__ float ea[kNChunk];
    if (tid < kNChunk)
        ea[tid] = expf(Acs[((size_t)(bi * kHeads + hi) * kNChunk + tid) * kChunk + kChunk - 1]);
    __syncthreads();
    float P[16];
    {
        float* pp = prevs + ((size_t)(bi * kNChunk + 0) * kHeads + hi) * (kP * kState);
        #pragma unroll
        for (int e = 0; e < 16; ++e) { P[e] = 0.f; pp[e * 256 + tid] = 0.f; }
    }
    for (int c = 1; c < kNChunk; ++c) {
        const float* sp = states + ((size_t)(bi * kNChunk + (c - 1)) * kHeads + hi) * (kP * kState);
        float* pp = prevs + ((size_t)(bi * kNChunk + c) * kHeads + hi) * (kP * kState);
        const float e_ = ea[c - 1];
        #pragma unroll
        for (int e = 0; e < 16; ++e) {
            P[e] = fmaf(e_, P[e], sp[e * 256 + tid]);
            pp[e * 256 + tid] = P[e];
        }
    }
}

// ---------------------------------------------------------------------------
// MFMA intra-chunk Y. Block = (b,c,h,lt). Output is written SLOT-MAJOR:
//   Yp[ks][t][8] with ks = (hi*64+p)/8 so the out-projection's
//   global_load_lds staging is linear+coalesced into its slot-major LDS.
// ---------------------------------------------------------------------------
__global__ __launch_bounds__(256)
void ychunk_mfma(const float* __restrict__ x, const bf16_t* __restrict__ Bb16,
                 const bf16_t* __restrict__ Cb16, const bf16_t* __restrict__ xdtT,
                 const float* __restrict__ Acs, const float* __restrict__ prevs,
                 const float* __restrict__ Dvec, bf16_t* __restrict__ Yp)
{
    const int blk = blockIdx.x;                  // ((bi*16+ci)*32+hi)*4 + lt
    const int lt = blk & 3;
    const int hi = (blk >> 2) & (kHeads - 1);
    const int ci = (blk >> 7) & (kNChunk - 1);
    const int bi = blk >> 11;
    __shared__ float acs_s[kChunk];
    __shared__ __bf16 Cs[64 * 72];
    __shared__ __bf16 Bs[64 * 72];
    __shared__ __bf16 Xt[64 * 72];   // XdtT[p][s]
    __shared__ __bf16 Sp[64 * 72];   // S' [l][s]
    const int tid = threadIdx.x;
    const int lane = tid & 63;
    const int wave = tid >> 6;
    const int l15 = lane & 15, quad = lane >> 4;
    const size_t rowbase = (size_t)bi * kSeq + ci * kChunk;
    const bf16_t* xdsrc = xdtT + ((size_t)((bi * kNChunk + ci) * kHeads + hi)) * (64 * 256);

    acs_s[tid] = Acs[((size_t)(bi * kHeads + hi) * kNChunk + ci) * kChunk + tid];
    // stage C l-tile (vec copy) and P (fp32 -> bf16) into Bs
    #pragma unroll
    for (int e = 0; e < 2; ++e) {
        const int u = e * 256 + tid;
        const int r = u >> 3, seg = (u & 7) * 8;
        *reinterpret_cast<bf16x8*>(&Cs[r * 72 + seg]) =
            *reinterpret_cast<const bf16x8*>(Cb16 + (rowbase + lt * 64 + r) * 64 + seg);
    }
    const float* pp = prevs + ((size_t)(bi * kNChunk + ci) * kHeads + hi) * (kP * kState);
    #pragma unroll
    for (int e = 0; e < 4; ++e) {
        const int idx = e * 1024 + tid * 4;
        const int r = idx >> 6, c = idx & 63;
        const float4 vp = *reinterpret_cast<const float4*>(pp + idx);
        bf16x4 p4;
        p4[0] = (__bf16)vp.x; p4[1] = (__bf16)vp.y;
        p4[2] = (__bf16)vp.z; p4[3] = (__bf16)vp.w;
        *reinterpret_cast<bf16x4*>(&Bs[r * 72 + c]) = p4;
    }
    __syncthreads();

    // A-frags (C rows of this wave's slice) — reused for Y_off and every S-tile
    bf16x8 af[2];
    af[0] = *reinterpret_cast<const bf16x8*>(&Cs[(wave * 16 + l15) * 72 + quad * 8]);
    af[1] = *reinterpret_cast<const bf16x8*>(&Cs[(wave * 16 + l15) * 72 + 32 + quad * 8]);

    // Y_off = (C @ P^T) * exp(acs[l])
    f32x4 yacc[4];
    #pragma unroll
    for (int ni = 0; ni < 4; ++ni) yacc[ni] = (f32x4){0.f, 0.f, 0.f, 0.f};
    #pragma unroll
    for (int ni = 0; ni < 4; ++ni) {
        const bf16x8 b0 = *reinterpret_cast<const bf16x8*>(&Bs[(ni * 16 + l15) * 72 + quad * 8]);
        const bf16x8 b1 = *reinterpret_cast<const bf16x8*>(&Bs[(ni * 16 + l15) * 72 + 32 + quad * 8]);
        yacc[ni] = __builtin_amdgcn_mfma_f32_16x16x32_bf16(af[0], b0, yacc[ni], 0, 0, 0);
        yacc[ni] = __builtin_amdgcn_mfma_f32_16x16x32_bf16(af[1], b1, yacc[ni], 0, 0, 0);
    }
    const int mrow = wave * 16 + quad * 4;   // C/D: row = quad*4+reg within 16x16
    {
        float es[4];
        #pragma unroll
        for (int reg = 0; reg < 4; ++reg) es[reg] = expf(acs_s[lt * 64 + mrow + reg]);
        #pragma unroll
        for (int ni = 0; ni < 4; ++ni)
            #pragma unroll
            for (int reg = 0; reg < 4; ++reg) yacc[ni][reg] *= es[reg];
    }

    for (int st = 0; st <= lt; ++st) {
        __syncthreads();   // everyone done reading Bs/Xt/Sp from previous stage
        // stage B s-tile and XdtT s-slice (pure vec copies)
        #pragma unroll
        for (int e = 0; e < 2; ++e) {
            const int u = e * 256 + tid;
            const int r = u >> 3, seg = (u & 7) * 8;
            *reinterpret_cast<bf16x8*>(&Bs[r * 72 + seg]) =
                *reinterpret_cast<const bf16x8*>(Bb16 + (rowbase + st * 64 + r) * 64 + seg);
            *reinterpret_cast<bf16x8*>(&Xt[r * 72 + seg]) =
                *reinterpret_cast<const bf16x8*>(xdsrc + r * 256 + st * 64 + seg);
        }
        __syncthreads();
        // S = C_lt(slice) @ B_st^T
        f32x4 sacc[4];
        #pragma unroll
        for (int ni = 0; ni < 4; ++ni) sacc[ni] = (f32x4){0.f, 0.f, 0.f, 0.f};
        #pragma unroll
        for (int ni = 0; ni < 4; ++ni) {
            const bf16x8 b0 = *reinterpret_cast<const bf16x8*>(&Bs[(ni * 16 + l15) * 72 + quad * 8]);
            const bf16x8 b1 = *reinterpret_cast<const bf16x8*>(&Bs[(ni * 16 + l15) * 72 + 32 + quad * 8]);
            sacc[ni] = __builtin_amdgcn_mfma_f32_16x16x32_bf16(af[0], b0, sacc[ni], 0, 0, 0);
            sacc[ni] = __builtin_amdgcn_mfma_f32_16x16x32_bf16(af[1], b1, sacc[ni], 0, 0, 0);
        }
        // decay + causal mask -> S' bf16
        #pragma unroll
        for (int reg = 0; reg < 4; ++reg) {
            const int l = lt * 64 + mrow + reg;
            const float al = acs_s[l];
            #pragma unroll
            for (int ni = 0; ni < 4; ++ni) {
                const int scol = ni * 16 + l15;
                const int sg = st * 64 + scol;
                float v = sacc[ni][reg] * expf(al - acs_s[sg]);
                if (st == lt && sg > l) v = 0.f;
                Sp[(mrow + reg) * 72 + scol] = (__bf16)v;
            }
        }
        __syncthreads();   // FENCE: S' writes visible (and compiler-ordered) before reads
        // Y += S' @ XdtT
        const bf16x8 as0 = *reinterpret_cast<const bf16x8*>(&Sp[(wave * 16 + l15) * 72 + quad * 8]);
        const bf16x8 as1 = *reinterpret_cast<const bf16x8*>(&Sp[(wave * 16 + l15) * 72 + 32 + quad * 8]);
        #pragma unroll
        for (int ni = 0; ni < 4; ++ni) {
            const bf16x8 x0 = *reinterpret_cast<const bf16x8*>(&Xt[(ni * 16 + l15) * 72 + quad * 8]);
            const bf16x8 x1 = *reinterpret_cast<const bf16x8*>(&Xt[(ni * 16 + l15) * 72 + 32 + quad * 8]);
            yacc[ni] = __builtin_amdgcn_mfma_f32_16x16x32_bf16(as0, x0, yacc[ni], 0, 0, 0);
            yacc[ni] = __builtin_amdgcn_mfma_f32_16x16x32_bf16(as1, x1, yacc[ni], 0, 0, 0);
        }
    }

    // epilogue: += D*x (fp32 x input), store bf16 Y in SLOT-MAJOR layout
    const float Dh = Dvec[hi];
    #pragma unroll
    for (int reg = 0; reg < 4; ++reg) {
        const size_t tg = rowbase + lt * 64 + mrow + reg;
        #pragma unroll
        for (int ni = 0; ni < 4; ++ni) {
            const int p = ni * 16 + l15;
            const float v = yacc[ni][reg] + Dh * x[tg * kDModel + hi * kP + p];
            // ks = (hi*64 + p) >> 3, j = p & 7
            Yp[((size_t)(hi * 8 + (p >> 3)) * (size_t)kM + tg) * 8 + (p & 7)] = (bf16_t)v;
        }
    }
}

extern "C" void kernel_launch(void* const* d_in, const int* in_sizes, int n_in,
                              void* d_out, int out_size, void* d_ws, size_t ws_size,
                              hipStream_t stream)
{
    (void)in_sizes; (void)n_in; (void)out_size; (void)ws_size;
    const float* x     = (const float*)d_in[0];
    const float* A_log = (const float*)d_in[1];
    const float* Dvec  = (const float*)d_in[2];
    const float* B_w   = (const float*)d_in[3];
    const float* B_b   = (const float*)d_in[4];
    const float* C_w   = (const float*)d_in[5];
    const float* C_b   = (const float*)d_in[6];
    const float* dt_w  = (const float*)d_in[7];
    const float* dt_b  = (const float*)d_in[8];
    const float* out_w = (const float*)d_in[9];
    const float* out_b = (const float*)d_in[10];
    float* out = (float*)d_out;

    // workspace layout
    float* ws = (float*)d_ws;
    float* dtm    = ws;                                                  // 2*4096*32
    float* Acs    = dtm + (size_t)kM * kHeads;                           // 2*32*16*256
    float* states = Acs + (size_t)kBatch * kHeads * kNChunk * kChunk;    // 2*16*32*64*64
    float* prevs  = states + (size_t)kBatch * kNChunk * kHeads * kP * kState;
    bf16_t* xb    = (bf16_t*)(prevs + (size_t)kBatch * kNChunk * kHeads * kP * kState);
    bf16_t* Y     = xb;                               // ALIAS: xb dead after xdtT_kernel
    bf16_t* Bb16  = xb + (size_t)kM * kDModel;        // [t][64]
    bf16_t* Cb16  = Bb16 + (size_t)kM * kState;       // [t][64]
    bf16_t* xdtT  = Cb16 + (size_t)kM * kState;       // [(b,c,h)][64][256]
    bf16_t* bTg   = xdtT + (size_t)kM * kDModel;      // [(b,c)][64][256]
    bf16_t* wcat  = bTg + (size_t)kBatch * kNChunk * kState * kChunk;
    bf16_t* wob   = wcat + (size_t)256 * kDModel;     // bf16 out_w, SLOT-MAJOR [256][2048][8]

    const dim3 blk(256);
    // dtype converts / packs
    cvt_bf16_kernel<<<dim3(kM * kDModel / 1024), blk, 0, stream>>>(x, xb, kM * kDModel);
    pack_wob_kernel<<<dim3(kDModel * 256 / 256), blk, 0, stream>>>(out_w, wob);
    pack_w_kernel<<<dim3(256 * kDModel / 256), blk, 0, stream>>>(B_w, C_w, dt_w, wcat);
    // fused B/C/dt projection (MFMA) -> bf16 B, bf16 C, fp32 softplus dt
    gemm_mfma<1><<<dim3(2, kM / 128), blk, 0, stream>>>(xb, wcat, kDModel, 0,
                                                        B_b, C_b, dt_b,
                                                        nullptr, Bb16, Cb16, dtm);
    // per-chunk cumulative decay
    dtcumsum_kernel<<<dim3(kBatch * kHeads * kNChunk), dim3(kChunk), 0, stream>>>(dtm, A_log, Acs);
    // B chunk transpose (shared across heads)
    bT_kernel<<<dim3(kBatch * kNChunk), blk, 0, stream>>>(Bb16, bTg);
    // xdt transposed per (b,c,h)  [last reader of xb]
    xdtT_kernel<<<dim3(kBatch * kNChunk * kHeads), blk, 0, stream>>>(xb, dtm, xdtT);
    // per-chunk end states (MFMA)
    states_mfma<<<dim3(kBatch * kNChunk * kHeads), blk, 0, stream>>>(xdtT, bTg, Acs, states);
    // inter-chunk recurrence (16 steps)
    chunkscan_kernel<<<dim3(kBatch * kHeads), blk, 0, stream>>>(states, Acs, prevs);
    // intra-chunk Y (MFMA)  [writes Yp == xb alias, slot-major]
    ychunk_mfma<<<dim3(kBatch * kNChunk * kHeads * 4), blk, 0, stream>>>(
        x, Bb16, Cb16, xdtT, Acs, prevs, Dvec, Y);
    // out-projection: 256x256 triple-buffered counted-vmcnt MFMA GEMM
    gemm256_out<<<dim3(256), dim3(512), 0, stream>>>(Y, wob, out_b, out);
}

// Round 2
// 351.867 us; speedup vs baseline: 1.1896x; 1.0911x over previous
//
#include <hip/hip_runtime.h>
#include <hip/hip_bf16.h>
#include <math.h>

namespace {
constexpr int kDModel = 2048;
constexpr int kHeads  = 32;
constexpr int kState  = 64;
constexpr int kP      = 64;    // head dim = D_MODEL / N_HEADS
constexpr int kChunk  = 256;
constexpr int kNChunk = 16;    // SEQLEN / CHUNK
constexpr int kBatch  = 2;
constexpr int kSeq    = 4096;
constexpr int kM      = kBatch * kSeq;  // 8192 rows
}

typedef __bf16 bf16_t;
typedef __attribute__((ext_vector_type(8))) __bf16 bf16x8;
typedef __attribute__((ext_vector_type(4))) __bf16 bf16x4;
typedef __attribute__((ext_vector_type(4))) float f32x4;

__device__ __forceinline__ void gload_lds16(const void* g, void* l) {
    __builtin_amdgcn_global_load_lds(
        (const __attribute__((address_space(1))) void*)g,
        (__attribute__((address_space(3))) void*)l,
        16, 0, 0);
}

// ---------------------------------------------------------------------------
// B/C/dt projection GEMM: 64x128 tile -> grid (2, 128) = 256 blocks (full CU
// coverage; the old 128x128 used only 128 blocks = half the chip).
// 4 waves in 2x2; each wave 32x64 via 2x4 of 16x16x32 MFMAs. BK=32.
// Epilogue: bf16 B (o0h), bf16 C (o1h), fp32 softplus dt (o2f).
// ---------------------------------------------------------------------------
__global__ __launch_bounds__(256)
void gemm_bcdt(const bf16_t* __restrict__ A, const bf16_t* __restrict__ W,
               const float* __restrict__ b0, const float* __restrict__ b1,
               const float* __restrict__ b2,
               bf16_t* __restrict__ o0h, bf16_t* __restrict__ o1h,
               float* __restrict__ o2f)
{
    constexpr int K = kDModel;
    __shared__ __bf16 AstS[64 * 32];
    __shared__ __bf16 WstS[128 * 32];
    const int tid  = threadIdx.x;
    const int lane = tid & 63;
    const int wave = tid >> 6;
    const int wm = (wave >> 1) * 32;
    const int wn = (wave & 1) * 64;
    const int l15 = lane & 15, quad = lane >> 4;
    const int m0 = blockIdx.y * 64;
    const int n0 = blockIdx.x * 128;
    const int u0 = tid, u1 = tid + 256;   // W staging 16B units

    f32x4 acc[2][4];
    #pragma unroll
    for (int i = 0; i < 2; ++i)
        #pragma unroll
        for (int j = 0; j < 4; ++j)
            acc[i][j] = (f32x4){0.f, 0.f, 0.f, 0.f};

    for (int k0 = 0; k0 < K; k0 += 32) {
        gload_lds16(A + (size_t)(m0 + (tid >> 2)) * K + k0 + (tid & 3) * 8, AstS + tid * 8);
        gload_lds16(W + (size_t)(n0 + (u0 >> 2)) * K + k0 + (u0 & 3) * 8, WstS + u0 * 8);
        gload_lds16(W + (size_t)(n0 + (u1 >> 2)) * K + k0 + (u1 & 3) * 8, WstS + u1 * 8);
        __syncthreads();
        bf16x8 af[2], bfr[4];
        #pragma unroll
        for (int mi = 0; mi < 2; ++mi)
            af[mi] = *reinterpret_cast<const bf16x8*>(&AstS[(wm + mi * 16 + l15) * 32 + quad * 8]);
        #pragma unroll
        for (int ni = 0; ni < 4; ++ni)
            bfr[ni] = *reinterpret_cast<const bf16x8*>(&WstS[(wn + ni * 16 + l15) * 32 + quad * 8]);
        #pragma unroll
        for (int mi = 0; mi < 2; ++mi)
            #pragma unroll
            for (int ni = 0; ni < 4; ++ni)
                acc[mi][ni] = __builtin_amdgcn_mfma_f32_16x16x32_bf16(
                    af[mi], bfr[ni], acc[mi][ni], 0, 0, 0);
        __syncthreads();
    }

    // C/D layout: col = lane&15, row = quad*4 + reg  [m89-verified]
    #pragma unroll
    for (int mi = 0; mi < 2; ++mi) {
        #pragma unroll
        for (int reg = 0; reg < 4; ++reg) {
            const int r = m0 + wm + mi * 16 + quad * 4 + reg;
            #pragma unroll
            for (int ni = 0; ni < 4; ++ni) {
                const float v = acc[mi][ni][reg];
                const int n = n0 + wn + ni * 16 + l15;
                if (n < 64) {
                    o0h[(size_t)r * 64 + n] = (bf16_t)(v + b0[n]);
                } else if (n < 128) {
                    o1h[(size_t)r * 64 + (n - 64)] = (bf16_t)(v + b1[n - 64]);
                } else if (n < 160) {
                    float z = v + b2[n - 128];
                    o2f[(size_t)r * 32 + (n - 128)] = (z > 20.f) ? z : log1pf(expf(z));
                }
            }
        }
    }
}

// ---------------------------------------------------------------------------
// Out-projection GEMM: 256x256 tile, BK=32, 8 waves (2Mx4N), triple-buffered
// LDS (96KB), raw s_barrier + counted vmcnt(4), slot-major LDS layout
// (conflict-free ds_read_b128, verified: SQ_LDS_BANK_CONFLICT = 0).
//   Ap[ks][m][8], Bp[ks][n][8]  (ks = k/8)
// XCD swizzle: **m-panel per XCD** — XCD x owns m-tiles 4x..4x+3 (4 MB of A,
// fits the 4 MB private L2 and is read once) and streams all of W (8.4 MB,
// shared across XCDs via L3). Per-K-step XCD working set: 4x16 + 8x16 =
// 192 KB (was 528 KB with n-panel-per-XCD).
// ---------------------------------------------------------------------------
__global__ __launch_bounds__(512, 2)
void gemm256_out(const bf16_t* __restrict__ Ap, const bf16_t* __restrict__ Bp,
                 const float* __restrict__ bias, float* __restrict__ C)
{
    constexpr int M = 8192, N = 2048, NT = 2048 / 32;  // 64 K-tiles
    __shared__ __bf16 Ab[3][4 * 256 * 8];   // [buf][q*256 + row][8]
    __shared__ __bf16 Bb[3][4 * 256 * 8];
    const int tid  = threadIdx.x;
    const int lane = tid & 63;
    const int wave = tid >> 6;
    const int l15 = lane & 15, quad = lane >> 4;
    // bijective m-panel-per-XCD swizzle: XCD = bid&7 (dispatch round-robin)
    const int bid = blockIdx.x;
    const int mt = (bid & 7) * 4 + ((bid >> 3) & 3);   // 0..31
    const int nt = bid >> 5;                           // 0..7
    const int m0 = mt * 256;
    const int n0 = nt * 256;
    const int wm = (wave >> 2) * 128;   // 0 or 128
    const int wn = (wave & 3) * 64;     // 0,64,128,192

    const int u0 = tid, u1 = tid + 512;   // staging 16B units, q = u>>8, r = u&255
    auto stage = [&](int t2, int stb) {
        const int ks0 = t2 * 4;
        const bf16_t* As = Ap + ((size_t)ks0 * M + m0) * 8;
        const bf16_t* Bs = Bp + ((size_t)ks0 * N + n0) * 8;
        __bf16* Al = &Ab[stb][0];
        __bf16* Bl = &Bb[stb][0];
        gload_lds16(As + ((size_t)(u0 >> 8) * M + (u0 & 255)) * 8, Al + u0 * 8);
        gload_lds16(As + ((size_t)(u1 >> 8) * M + (u1 & 255)) * 8, Al + u1 * 8);
        gload_lds16(Bs + ((size_t)(u0 >> 8) * N + (u0 & 255)) * 8, Bl + u0 * 8);
        gload_lds16(Bs + ((size_t)(u1 >> 8) * N + (u1 & 255)) * 8, Bl + u1 * 8);
    };

    f32x4 acc[8][4];
    #pragma unroll
    for (int i = 0; i < 8; ++i)
        #pragma unroll
        for (int j = 0; j < 4; ++j)
            acc[i][j] = (f32x4){0.f, 0.f, 0.f, 0.f};

    // prologue: tiles 0 and 1 in flight; wait for tile 0 (4 newest may fly)
    stage(0, 0);
    stage(1, 1);
    asm volatile("s_waitcnt vmcnt(4)" ::: "memory");
    __builtin_amdgcn_s_barrier();

    int cur = 0;
    for (int t = 0; t < NT; ++t) {
        const __bf16* Ac = &Ab[cur][0];
        const __bf16* Bc = &Bb[cur][0];
        int stb = cur + 2; if (stb >= 3) stb -= 3;

        // ---- phase A: frags (rows wm..wm+63) + all B frags; prefetch t+2
        bf16x8 af[4], bfr[4];
        #pragma unroll
        for (int mi = 0; mi < 4; ++mi)
            af[mi] = *reinterpret_cast<const bf16x8*>(
                &Ac[(quad * 256 + wm + mi * 16 + l15) * 8]);
        #pragma unroll
        for (int nj = 0; nj < 4; ++nj)
            bfr[nj] = *reinterpret_cast<const bf16x8*>(
                &Bc[(quad * 256 + wn + nj * 16 + l15) * 8]);
        if (t < NT - 2) stage(t + 2, stb);
        __builtin_amdgcn_s_setprio(1);
        #pragma unroll
        for (int mi = 0; mi < 4; ++mi)
            #pragma unroll
            for (int nj = 0; nj < 4; ++nj)
                acc[mi][nj] = __builtin_amdgcn_mfma_f32_16x16x32_bf16(
                    af[mi], bfr[nj], acc[mi][nj], 0, 0, 0);
        __builtin_amdgcn_s_setprio(0);

        // ---- phase B: frags (rows wm+64..wm+127), reuse B frags
        #pragma unroll
        for (int mi = 0; mi < 4; ++mi)
            af[mi] = *reinterpret_cast<const bf16x8*>(
                &Ac[(quad * 256 + wm + 64 + mi * 16 + l15) * 8]);
        __builtin_amdgcn_s_setprio(1);
        #pragma unroll
        for (int mi = 0; mi < 4; ++mi)
            #pragma unroll
            for (int nj = 0; nj < 4; ++nj)
                acc[4 + mi][nj] = __builtin_amdgcn_mfma_f32_16x16x32_bf16(
                    af[mi], bfr[nj], acc[4 + mi][nj], 0, 0, 0);
        __builtin_amdgcn_s_setprio(0);

        // ---- tile boundary: tile t+1 must be landed; t+2's 4 loads may fly
        if (t < NT - 2) {
            asm volatile("s_waitcnt vmcnt(4)" ::: "memory");
        } else if (t < NT - 1) {
            asm volatile("s_waitcnt vmcnt(0)" ::: "memory");
        }
        if (t < NT - 1) __builtin_amdgcn_s_barrier();
        cur = cur + 1; if (cur == 3) cur = 0;
    }

    // epilogue: C = acc + bias
    float bia[4];
    #pragma unroll
    for (int nj = 0; nj < 4; ++nj) bia[nj] = bias[n0 + wn + nj * 16 + l15];
    #pragma unroll
    for (int mi = 0; mi < 8; ++mi) {
        #pragma unroll
        for (int reg = 0; reg < 4; ++reg) {
            const int r = m0 + wm + mi * 16 + quad * 4 + reg;
            #pragma unroll
            for (int nj = 0; nj < 4; ++nj) {
                const int c = n0 + wn + nj * 16 + l15;
                C[(size_t)r * N + c] = acc[mi][nj][reg] + bia[nj];
            }
        }
    }
}

// float -> bf16 convert, 4 elems/thread
__global__ __launch_bounds__(256)
void cvt_bf16_kernel(const float* __restrict__ src, bf16_t* __restrict__ dst, int n)
{
    const int i = (blockIdx.x * 256 + threadIdx.x) * 4;
    if (i + 3 < n) {
        const float4 v = *reinterpret_cast<const float4*>(src + i);
        dst[i + 0] = (bf16_t)v.x;
        dst[i + 1] = (bf16_t)v.y;
        dst[i + 2] = (bf16_t)v.z;
        dst[i + 3] = (bf16_t)v.w;
    }
}

// out_w fp32 [2048][2048] (row n, col k) -> slot-major bf16 Wp[ks][n][8]
__global__ __launch_bounds__(256)
void pack_wob_kernel(const float* __restrict__ W, bf16_t* __restrict__ Wp)
{
    const int idx = blockIdx.x * 256 + threadIdx.x;   // 2048*256 units of 16B
    const int n = idx >> 8, ks = idx & 255;           // coalesced reads
    const float4 v0 = *reinterpret_cast<const float4*>(W + (size_t)n * 2048 + ks * 8);
    const float4 v1 = *reinterpret_cast<const float4*>(W + (size_t)n * 2048 + ks * 8 + 4);
    bf16x8 o;
    o[0] = (__bf16)v0.x; o[1] = (__bf16)v0.y; o[2] = (__bf16)v0.z; o[3] = (__bf16)v0.w;
    o[4] = (__bf16)v1.x; o[5] = (__bf16)v1.y; o[6] = (__bf16)v1.z; o[7] = (__bf16)v1.w;
    *reinterpret_cast<bf16x8*>(Wp + ((size_t)ks * 2048 + n) * 8) = o;
}

// Concat [B_w;C_w;dt_w] into bf16 [256,2048], rows 160..255 zero
__global__ __launch_bounds__(256)
void pack_w_kernel(const float* __restrict__ B_w, const float* __restrict__ C_w,
                   const float* __restrict__ dt_w, bf16_t* __restrict__ wcat)
{
    const int idx = blockIdx.x * 256 + threadIdx.x;   // 256*2048 total
    const int r = idx >> 11, k = idx & 2047;
    float v = 0.f;
    if (r < 64)       v = B_w[r * 2048 + k];
    else if (r < 128) v = C_w[(r - 64) * 2048 + k];
    else if (r < 160) v = dt_w[(r - 128) * 2048 + k];
    wcat[idx] = (bf16_t)v;
}

// Per (b,h,chunk): Acs[l] = inclusive cumsum_l( dt[l] * A[h] ), A = -exp(A_log)
__global__ __launch_bounds__(kChunk)
void dtcumsum_kernel(const float* __restrict__ dtm, const float* __restrict__ A_log,
                     float* __restrict__ Acs)
{
    const int blk = blockIdx.x;                  // (bi*kHeads+hi)*kNChunk + ci
    const int ci = blk & (kNChunk - 1);
    const int hi = (blk >> 4) & (kHeads - 1);
    const int bi = blk >> 9;
    const int t = threadIdx.x;
    const float Ah = -expf(A_log[hi]);
    __shared__ float s[kChunk];
    s[t] = dtm[((size_t)bi * kSeq + ci * kChunk + t) * kHeads + hi] * Ah;
    __syncthreads();
    for (int off = 1; off < kChunk; off <<= 1) {
        const float add = (t >= off) ? s[t - off] : 0.f;
        __syncthreads();
        s[t] += add;
        __syncthreads();
    }
    Acs[((size_t)(bi * kHeads + hi) * kNChunk + ci) * kChunk + t] = s[t];
}

// Transpose one chunk of B: bTg[b,c][n][l] = Bb16[(b,c,l)][n]
__global__ __launch_bounds__(256)
void bT_kernel(const bf16_t* __restrict__ Bb16, bf16_t* __restrict__ bTg)
{
    const int ci = blockIdx.x & (kNChunk - 1);
    const int bi = blockIdx.x >> 4;
    const size_t rowbase = (size_t)bi * kSeq + ci * kChunk;
    __shared__ __bf16 T[64 * 264];
    const int tid = threadIdx.x;        // = row l
    bf16x8 v[8];
    #pragma unroll
    for (int e = 0; e < 8; ++e)
        v[e] = *reinterpret_cast<const bf16x8*>(Bb16 + (rowbase + tid) * 64 + e * 8);
    #pragma unroll
    for (int e = 0; e < 8; ++e)
        #pragma unroll
        for (int j = 0; j < 8; ++j)
            T[(e * 8 + j) * 264 + tid] = v[e][j];
    __syncthreads();
    const int n = tid >> 2, seg = (tid & 3) * 64;
    bf16_t* dst = bTg + ((size_t)(bi * kNChunk + ci)) * (64 * 256) + n * 256 + seg;
    #pragma unroll
    for (int j = 0; j < 8; ++j) {
        *reinterpret_cast<bf16x8*>(dst + j * 8) =
            *reinterpret_cast<const bf16x8*>(&T[n * 264 + seg + j * 8]);
    }
}

// xdtT[(b,c,h)][p][l] = bf16( xb[t, h*64+p] * dt[t,h] ),  t = rowbase+l
__global__ __launch_bounds__(256)
void xdtT_kernel(const bf16_t* __restrict__ xb, const float* __restrict__ dtm,
                 bf16_t* __restrict__ xdtT)
{
    const int blk = blockIdx.x;                  // (bi*16+ci)*32+hi
    const int hi = blk & (kHeads - 1);
    const int ci = (blk >> 5) & (kNChunk - 1);
    const int bi = blk >> 9;
    const size_t rowbase = (size_t)bi * kSeq + ci * kChunk;
    __shared__ __bf16 T[64 * 264];
    const int tid = threadIdx.x;        // = row l
    const float d = dtm[(rowbase + tid) * kHeads + hi];
    bf16x8 v[8];
    #pragma unroll
    for (int e = 0; e < 8; ++e)
        v[e] = *reinterpret_cast<const bf16x8*>(xb + (rowbase + tid) * kDModel + hi * kP + e * 8);
    #pragma unroll
    for (int e = 0; e < 8; ++e)
        #pragma unroll
        for (int j = 0; j < 8; ++j)
            T[(e * 8 + j) * 264 + tid] = (__bf16)((float)v[e][j] * d);
    __syncthreads();
    const int p = tid >> 2, seg = (tid & 3) * 64;
    bf16_t* dst = xdtT + (size_t)blk * (64 * 256) + p * 256 + seg;
    #pragma unroll
    for (int j = 0; j < 8; ++j) {
        *reinterpret_cast<bf16x8*>(dst + j * 8) =
            *reinterpret_cast<const bf16x8*>(&T[p * 264 + seg + j * 8]);
    }
}

// ---------------------------------------------------------------------------
// MFMA chunk states: states[(b,c,h)][p][n] = sum_l xdtT[p][l]*dec[l]*B[l][n]
// ---------------------------------------------------------------------------
__global__ __launch_bounds__(256)
void states_mfma(const bf16_t* __restrict__ xdtT, const bf16_t* __restrict__ bTg,
                 const float* __restrict__ Acs, float* __restrict__ states)
{
    const int blk = blockIdx.x;                  // (bi*16+ci)*32+hi
    const int hi = blk & (kHeads - 1);
    const int ci = (blk >> 5) & (kNChunk - 1);
    const int bi = blk >> 9;
    __shared__ __bf16 Xa[64 * 264];
    __shared__ __bf16 Bt[64 * 264];
    __shared__ float dec[kChunk];
    const int tid = threadIdx.x;
    const int lane = tid & 63;
    const int wave = tid >> 6;
    const int l15 = lane & 15, quad = lane >> 4;

    const float* acs = Acs + ((size_t)(bi * kHeads + hi) * kNChunk + ci) * kChunk;
    dec[tid] = expf(acs[kChunk - 1] - acs[tid]);   // <= 1
    __syncthreads();

    const bf16_t* bsrc = bTg + ((size_t)(bi * kNChunk + ci)) * (64 * 256);
    const bf16_t* xsrc = xdtT + (size_t)blk * (64 * 256);
    #pragma unroll
    for (int e = 0; e < 8; ++e) {
        const int u = e * 256 + tid;
        const int r = u >> 5, seg = (u & 31) * 8;
        *reinterpret_cast<bf16x8*>(&Bt[r * 264 + seg]) =
            *reinterpret_cast<const bf16x8*>(bsrc + r * 256 + seg);
        bf16x8 xv = *reinterpret_cast<const bf16x8*>(xsrc + r * 256 + seg);
        bf16x8 xo;
        #pragma unroll
        for (int j = 0; j < 8; ++j)
            xo[j] = (__bf16)((float)xv[j] * dec[seg + j]);
        *reinterpret_cast<bf16x8*>(&Xa[r * 264 + seg]) = xo;
    }
    __syncthreads();

    f32x4 acc[4];
    #pragma unroll
    for (int ni = 0; ni < 4; ++ni) acc[ni] = (f32x4){0.f, 0.f, 0.f, 0.f};
    #pragma unroll
    for (int kk = 0; kk < 8; ++kk) {
        const bf16x8 af = *reinterpret_cast<const bf16x8*>(
            &Xa[(wave * 16 + l15) * 264 + kk * 32 + quad * 8]);
        #pragma unroll
        for (int ni = 0; ni < 4; ++ni) {
            const bf16x8 bf = *reinterpret_cast<const bf16x8*>(
                &Bt[(ni * 16 + l15) * 264 + kk * 32 + quad * 8]);
            acc[ni] = __builtin_amdgcn_mfma_f32_16x16x32_bf16(af, bf, acc[ni], 0, 0, 0);
        }
    }
    float* sp = states + (size_t)blk * (kP * kState);
    #pragma unroll
    for (int reg = 0; reg < 4; ++reg) {
        const int p = wave * 16 + quad * 4 + reg;
        #pragma unroll
        for (int ni = 0; ni < 4; ++ni)
            sp[(size_t)p * kState + ni * 16 + l15] = acc[ni][reg];
    }
}

// prevs[b,0,h]=0 ; prevs[b,c,h] = exp(a[c-1])*prevs[b,c-1,h] + states[b,c-1,h]
// Fully parallel over the 4096 (p,n) elements: grid = (b,h,quarter) = 1024
// blocks (was 64 blocks with a 16-element serial inner loop per thread).
__global__ __launch_bounds__(256)
void chunkscan_kernel(const float* __restrict__ states, const float* __restrict__ Acs,
                      float* __restrict__ prevs)
{
    const int q  = blockIdx.x & 15;
    const int hi = (blockIdx.x >> 4) & (kHeads - 1);
    const int bi = blockIdx.x >> 9;
    const int e  = q * 256 + threadIdx.x;          // element in [0, 4096)
    __shared__ float ea[kNChunk];
    if (threadIdx.x < kNChunk)
        ea[threadIdx.x] = expf(Acs[((size_t)(bi * kHeads + hi) * kNChunk + threadIdx.x)
                                   * kChunk + kChunk - 1]);
    __syncthreads();
    float P = 0.f;
    prevs[((size_t)(bi * kNChunk + 0) * kHeads + hi) * (kP * kState) + e] = 0.f;
    for (int c = 1; c < kNChunk; ++c) {
        P = fmaf(ea[c - 1], P,
                 states[((size_t)(bi * kNChunk + (c - 1)) * kHeads + hi) * (kP * kState) + e]);
        prevs[((size_t)(bi * kNChunk + c) * kHeads + hi) * (kP * kState) + e] = P;
    }
}

// ---------------------------------------------------------------------------
// MFMA intra-chunk Y. Block = (b,c,h,lt). Output is written SLOT-MAJOR:
//   Yp[ks][t][8] with ks = (hi*64+p)/8 so the out-projection's
//   global_load_lds staging is linear+coalesced into its slot-major LDS.
// ---------------------------------------------------------------------------
__global__ __launch_bounds__(256)
void ychunk_mfma(const float* __restrict__ x, const bf16_t* __restrict__ Bb16,
                 const bf16_t* __restrict__ Cb16, const bf16_t* __restrict__ xdtT,
                 const float* __restrict__ Acs, const float* __restrict__ prevs,
                 const float* __restrict__ Dvec, bf16_t* __restrict__ Yp)
{
    const int blk = blockIdx.x;                  // ((bi*16+ci)*32+hi)*4 + lt
    const int lt = blk & 3;
    const int hi = (blk >> 2) & (kHeads - 1);
    const int ci = (blk >> 7) & (kNChunk - 1);
    const int bi = blk >> 11;
    __shared__ float acs_s[kChunk];
    __shared__ __bf16 Cs[64 * 72];
    __shared__ __bf16 Bs[64 * 72];
    __shared__ __bf16 Xt[64 * 72];   // XdtT[p][s]
    __shared__ __bf16 Sp[64 * 72];   // S' [l][s]
    const int tid = threadIdx.x;
    const int lane = tid & 63;
    const int wave = tid >> 6;
    const int l15 = lane & 15, quad = lane >> 4;
    const size_t rowbase = (size_t)bi * kSeq + ci * kChunk;
    const bf16_t* xdsrc = xdtT + ((size_t)((bi * kNChunk + ci) * kHeads + hi)) * (64 * 256);

    acs_s[tid] = Acs[((size_t)(bi * kHeads + hi) * kNChunk + ci) * kChunk + tid];
    // stage C l-tile (vec copy) and P (fp32 -> bf16) into Bs
    #pragma unroll
    for (int e = 0; e < 2; ++e) {
        const int u = e * 256 + tid;
        const int r = u >> 3, seg = (u & 7) * 8;
        *reinterpret_cast<bf16x8*>(&Cs[r * 72 + seg]) =
            *reinterpret_cast<const bf16x8*>(Cb16 + (rowbase + lt * 64 + r) * 64 + seg);
    }
    const float* pp = prevs + ((size_t)(bi * kNChunk + ci) * kHeads + hi) * (kP * kState);
    #pragma unroll
    for (int e = 0; e < 4; ++e) {
        const int idx = e * 1024 + tid * 4;
        const int r = idx >> 6, c = idx & 63;
        const float4 vp = *reinterpret_cast<const float4*>(pp + idx);
        bf16x4 p4;
        p4[0] = (__bf16)vp.x; p4[1] = (__bf16)vp.y;
        p4[2] = (__bf16)vp.z; p4[3] = (__bf16)vp.w;
        *reinterpret_cast<bf16x4*>(&Bs[r * 72 + c]) = p4;
    }
    __syncthreads();

    // A-frags (C rows of this wave's slice) — reused for Y_off and every S-tile
    bf16x8 af[2];
    af[0] = *reinterpret_cast<const bf16x8*>(&Cs[(wave * 16 + l15) * 72 + quad * 8]);
    af[1] = *reinterpret_cast<const bf16x8*>(&Cs[(wave * 16 + l15) * 72 + 32 + quad * 8]);

    // Y_off = (C @ P^T) * exp(acs[l])
    f32x4 yacc[4];
    #pragma unroll
    for (int ni = 0; ni < 4; ++ni) yacc[ni] = (f32x4){0.f, 0.f, 0.f, 0.f};
    #pragma unroll
    for (int ni = 0; ni < 4; ++ni) {
        const bf16x8 b0 = *reinterpret_cast<const bf16x8*>(&Bs[(ni * 16 + l15) * 72 + quad * 8]);
        const bf16x8 b1 = *reinterpret_cast<const bf16x8*>(&Bs[(ni * 16 + l15) * 72 + 32 + quad * 8]);
        yacc[ni] = __builtin_amdgcn_mfma_f32_16x16x32_bf16(af[0], b0, yacc[ni], 0, 0, 0);
        yacc[ni] = __builtin_amdgcn_mfma_f32_16x16x32_bf16(af[1], b1, yacc[ni], 0, 0, 0);
    }
    const int mrow = wave * 16 + quad * 4;   // C/D: row = quad*4+reg within 16x16
    {
        float es[4];
        #pragma unroll
        for (int reg = 0; reg < 4; ++reg) es[reg] = expf(acs_s[lt * 64 + mrow + reg]);
        #pragma unroll
        for (int ni = 0; ni < 4; ++ni)
            #pragma unroll
            for (int reg = 0; reg < 4; ++reg) yacc[ni][reg] *= es[reg];
    }

    for (int st = 0; st <= lt; ++st) {
        __syncthreads();   // everyone done reading Bs/Xt/Sp from previous stage
        // stage B s-tile and XdtT s-slice (pure vec copies)
        #pragma unroll
        for (int e = 0; e < 2; ++e) {
            const int u = e * 256 + tid;
            const int r = u >> 3, seg = (u & 7) * 8;
            *reinterpret_cast<bf16x8*>(&Bs[r * 72 + seg]) =
                *reinterpret_cast<const bf16x8*>(Bb16 + (rowbase + st * 64 + r) * 64 + seg);
            *reinterpret_cast<bf16x8*>(&Xt[r * 72 + seg]) =
                *reinterpret_cast<const bf16x8*>(xdsrc + r * 256 + st * 64 + seg);
        }
        __syncthreads();
        // S = C_lt(slice) @ B_st^T
        f32x4 sacc[4];
        #pragma unroll
        for (int ni = 0; ni < 4; ++ni) sacc[ni] = (f32x4){0.f, 0.f, 0.f, 0.f};
        #pragma unroll
        for (int ni = 0; ni < 4; ++ni) {
            const bf16x8 b0 = *reinterpret_cast<const bf16x8*>(&Bs[(ni * 16 + l15) * 72 + quad * 8]);
            const bf16x8 b1 = *reinterpret_cast<const bf16x8*>(&Bs[(ni * 16 + l15) * 72 + 32 + quad * 8]);
            sacc[ni] = __builtin_amdgcn_mfma_f32_16x16x32_bf16(af[0], b0, sacc[ni], 0, 0, 0);
            sacc[ni] = __builtin_amdgcn_mfma_f32_16x16x32_bf16(af[1], b1, sacc[ni], 0, 0, 0);
        }
        // decay + causal mask -> S' bf16
        #pragma unroll
        for (int reg = 0; reg < 4; ++reg) {
            const int l = lt * 64 + mrow + reg;
            const float al = acs_s[l];
            #pragma unroll
            for (int ni = 0; ni < 4; ++ni) {
                const int scol = ni * 16 + l15;
                const int sg = st * 64 + scol;
                float v = sacc[ni][reg] * expf(al - acs_s[sg]);
                if (st == lt && sg > l) v = 0.f;
                Sp[(mrow + reg) * 72 + scol] = (__bf16)v;
            }
        }
        __syncthreads();   // FENCE: S' writes visible (and compiler-ordered) before reads
        // Y += S' @ XdtT
        const bf16x8 as0 = *reinterpret_cast<const bf16x8*>(&Sp[(wave * 16 + l15) * 72 + quad * 8]);
        const bf16x8 as1 = *reinterpret_cast<const bf16x8*>(&Sp[(wave * 16 + l15) * 72 + 32 + quad * 8]);
        #pragma unroll
        for (int ni = 0; ni < 4; ++ni) {
            const bf16x8 x0 = *reinterpret_cast<const bf16x8*>(&Xt[(ni * 16 + l15) * 72 + quad * 8]);
            const bf16x8 x1 = *reinterpret_cast<const bf16x8*>(&Xt[(ni * 16 + l15) * 72 + 32 + quad * 8]);
            yacc[ni] = __builtin_amdgcn_mfma_f32_16x16x32_bf16(as0, x0, yacc[ni], 0, 0, 0);
            yacc[ni] = __builtin_amdgcn_mfma_f32_16x16x32_bf16(as1, x1, yacc[ni], 0, 0, 0);
        }
    }

    // epilogue: += D*x (fp32 x input), store bf16 Y in SLOT-MAJOR layout
    const float Dh = Dvec[hi];
    #pragma unroll
    for (int reg = 0; reg < 4; ++reg) {
        const size_t tg = rowbase + lt * 64 + mrow + reg;
        #pragma unroll
        for (int ni = 0; ni < 4; ++ni) {
            const int p = ni * 16 + l15;
            const float v = yacc[ni][reg] + Dh * x[tg * kDModel + hi * kP + p];
            // ks = (hi*64 + p) >> 3, j = p & 7
            Yp[((size_t)(hi * 8 + (p >> 3)) * (size_t)kM + tg) * 8 + (p & 7)] = (bf16_t)v;
        }
    }
}

extern "C" void kernel_launch(void* const* d_in, const int* in_sizes, int n_in,
                              void* d_out, int out_size, void* d_ws, size_t ws_size,
                              hipStream_t stream)
{
    (void)in_sizes; (void)n_in; (void)out_size; (void)ws_size;
    const float* x     = (const float*)d_in[0];
    const float* A_log = (const float*)d_in[1];
    const float* Dvec  = (const float*)d_in[2];
    const float* B_w   = (const float*)d_in[3];
    const float* B_b   = (const float*)d_in[4];
    const float* C_w   = (const float*)d_in[5];
    const float* C_b   = (const float*)d_in[6];
    const float* dt_w  = (const float*)d_in[7];
    const float* dt_b  = (const float*)d_in[8];
    const float* out_w = (const float*)d_in[9];
    const float* out_b = (const float*)d_in[10];
    float* out = (float*)d_out;

    // workspace layout
    float* ws = (float*)d_ws;
    float* dtm    = ws;                                                  // 2*4096*32
    float* Acs    = dtm + (size_t)kM * kHeads;                           // 2*32*16*256
    float* states = Acs + (size_t)kBatch * kHeads * kNChunk * kChunk;    // 2*16*32*64*64
    float* prevs  = states + (size_t)kBatch * kNChunk * kHeads * kP * kState;
    bf16_t* xb    = (bf16_t*)(prevs + (size_t)kBatch * kNChunk * kHeads * kP * kState);
    bf16_t* Y     = xb;                               // ALIAS: xb dead after xdtT_kernel
    bf16_t* Bb16  = xb + (size_t)kM * kDModel;        // [t][64]
    bf16_t* Cb16  = Bb16 + (size_t)kM * kState;       // [t][64]
    bf16_t* xdtT  = Cb16 + (size_t)kM * kState;       // [(b,c,h)][64][256]
    bf16_t* bTg   = xdtT + (size_t)kM * kDModel;      // [(b,c)][64][256]
    bf16_t* wcat  = bTg + (size_t)kBatch * kNChunk * kState * kChunk;
    bf16_t* wob   = wcat + (size_t)256 * kDModel;     // bf16 out_w, SLOT-MAJOR [256][2048][8]

    const dim3 blk(256);
    // dtype converts / packs
    cvt_bf16_kernel<<<dim3(kM * kDModel / 1024), blk, 0, stream>>>(x, xb, kM * kDModel);
    pack_wob_kernel<<<dim3(kDModel * 256 / 256), blk, 0, stream>>>(out_w, wob);
    pack_w_kernel<<<dim3(256 * kDModel / 256), blk, 0, stream>>>(B_w, C_w, dt_w, wcat);
    // fused B/C/dt projection (MFMA), 64x128 tiles -> 256 blocks (full chip)
    gemm_bcdt<<<dim3(2, kM / 64), blk, 0, stream>>>(xb, wcat,
                                                    B_b, C_b, dt_b,
                                                    Bb16, Cb16, dtm);
    // per-chunk cumulative decay
    dtcumsum_kernel<<<dim3(kBatch * kHeads * kNChunk), dim3(kChunk), 0, stream>>>(dtm, A_log, Acs);
    // B chunk transpose (shared across heads)
    bT_kernel<<<dim3(kBatch * kNChunk), blk, 0, stream>>>(Bb16, bTg);
    // xdt transposed per (b,c,h)  [last reader of xb]
    xdtT_kernel<<<dim3(kBatch * kNChunk * kHeads), blk, 0, stream>>>(xb, dtm, xdtT);
    // per-chunk end states (MFMA)
    states_mfma<<<dim3(kBatch * kNChunk * kHeads), blk, 0, stream>>>(xdtT, bTg, Acs, states);
    // inter-chunk recurrence (parallel over elements, serial only in c)
    chunkscan_kernel<<<dim3(kBatch * kHeads * 16), blk, 0, stream>>>(states, Acs, prevs);
    // intra-chunk Y (MFMA)  [writes Yp == xb alias, slot-major]
    ychunk_mfma<<<dim3(kBatch * kNChunk * kHeads * 4), blk, 0, stream>>>(
        x, Bb16, Cb16, xdtT, Acs, prevs, Dvec, Y);
    // out-projection: 256x256 triple-buffered counted-vmcnt MFMA GEMM
    gemm256_out<<<dim3(256), dim3(512), 0, stream>>>(Y, wob, out_b, out);
}